// Round 10
// baseline (1277.141 us; speedup 1.0000x reference)
//
#include <hip/hip_runtime.h>
#include <cstddef>
#include <cstdint>

typedef __attribute__((ext_vector_type(8))) short bf16x8;
typedef __attribute__((ext_vector_type(4))) float f32x4;
typedef unsigned int u32t;
typedef unsigned short u16t;

__device__ inline u16t f2bf(float f) {
  union { float f; unsigned u; } c; c.f = f;
  return (u16t)((c.u + 0x7FFFu + ((c.u >> 16) & 1u)) >> 16);
}
__device__ inline float ubits(u32t u) { union { u32t u; float f; } c; c.u = u; return c.f; }
__device__ inline float bf2f(u16t u) { return ubits(((u32t)u) << 16); }
__device__ inline float fsig(float x) { return __builtin_amdgcn_rcpf(1.f + __expf(-x)); }
__device__ inline float ftanh(float x) {
  float t = __expf(-2.f * fabsf(x));
  return copysignf((1.f - t) * __builtin_amdgcn_rcpf(1.f + t), x);
}

// bf16 weight mats, row-major [128][128]:
// 0: Wzf  1: Wzh  2: Wr  3: Whf  4: Whh  5: Ur
__global__ __launch_bounds__(256) void conv_weights(
    const float* __restrict__ Wz, const float* __restrict__ Wr,
    const float* __restrict__ Ur, const float* __restrict__ Wh,
    short* __restrict__ out)
{
  int i = blockIdx.x * 256 + threadIdx.x;
  if (i >= 6 * 16384) return;
  int mat = i >> 14, idx = i & 16383;
  int o = idx >> 7, c = idx & 127;
  float v = 0.f;
  switch (mat) {
    case 0: v = Wz[o * 256 + c];        break;
    case 1: v = Wz[o * 256 + 128 + c];  break;
    case 2: v = Wr[o * 128 + c];        break;
    case 3: v = Wh[o * 256 + c];        break;
    case 4: v = Wh[o * 256 + 128 + c];  break;
    case 5: v = Ur[o * 128 + c];        break;
  }
  out[i] = (short)f2bf(v);
}

__global__ __launch_bounds__(256) void conv_fmess(const float* __restrict__ src,
                                                  u16t* __restrict__ dst, size_t n8)
{
  size_t i = (size_t)blockIdx.x * 256 + threadIdx.x;
  if (i >= n8) return;
  const float4 a = *reinterpret_cast<const float4*>(src + i * 8);
  const float4 b = *reinterpret_cast<const float4*>(src + i * 8 + 4);
  uint4 o;
  o.x = ((u32t)f2bf(a.y) << 16) | f2bf(a.x);
  o.y = ((u32t)f2bf(a.w) << 16) | f2bf(a.z);
  o.z = ((u32t)f2bf(b.y) << 16) | f2bf(b.x);
  o.w = ((u32t)f2bf(b.w) << 16) | f2bf(b.z);
  *reinterpret_cast<uint4*>(dst + i * 8) = o;
}

__global__ void detect64(const int* __restrict__ bg, int* __restrict__ flag) {
  int t = threadIdx.x;
  int v = bg[2 * t + 1];
  unsigned long long m = __ballot(v == 0);
  if (t == 0) *flag = (m == ~0ull) ? 1 : 0;
}

__global__ __launch_bounds__(256) void compact_bg(const int* __restrict__ bg,
                                                  const int* __restrict__ flag,
                                                  int* __restrict__ bg32, int n)
{
  int i = blockIdx.x * 256 + threadIdx.x;
  if (i < n) bg32[i] = (*flag) ? bg[2 * (size_t)i] : bg[i];
}

// ---- gather: load chunk c's 16 h-rows for this wave as A-fragments (2 lines/row) ----
#define ANLOAD(D0, D1, D2, D3, c) { \
  const u16t* rp_ = Hin + (size_t)idxs[c] * 128 + kg * 8; \
  D0 = *reinterpret_cast<const uint4*>(rp_); \
  D1 = *reinterpret_cast<const uint4*>(rp_ + 32); \
  D2 = *reinterpret_cast<const uint4*>(rp_ + 64); \
  D3 = *reinterpret_cast<const uint4*>(rp_ + 96); \
}

// ---- chunk body: stage to htile, (prefetch next), MFMA P = h@Ur^T slice, gate+reduce ----
#define CHUNK(c, A0, A1, A2, A3, B0, B1, B2, B3, LAST) { \
  __syncthreads();  /* htile free (prev chunk's reads done) */ \
  { int slot_ = cg * 16 + cl; \
    *reinterpret_cast<uint4*>(htg + slot_ * 140 + 0  + kg * 8) = A0; \
    *reinterpret_cast<uint4*>(htg + slot_ * 140 + 32 + kg * 8) = A1; \
    *reinterpret_cast<uint4*>(htg + slot_ * 140 + 64 + kg * 8) = A2; \
    *reinterpret_cast<uint4*>(htg + slot_ * 140 + 96 + kg * 8) = A3; } \
  if (!(LAST)) { ANLOAD(B0, B1, B2, B3, (c) + 1) } \
  __syncthreads();  /* htile ready */ \
  f32x4 pac[4][2]; \
  _Pragma("unroll") for (int t = 0; t < 4; ++t) { \
    pac[t][0] = (f32x4){0.f, 0.f, 0.f, 0.f}; pac[t][1] = (f32x4){0.f, 0.f, 0.f, 0.f}; } \
  _Pragma("unroll") for (int ks = 0; ks < 4; ++ks) { \
    bf16x8 w0_ = *reinterpret_cast<const bf16x8*>(Ur + (size_t)(ncol + cl) * 128 + ks * 32 + kg * 8); \
    bf16x8 w1_ = *reinterpret_cast<const bf16x8*>(Ur + (size_t)(ncol + 16 + cl) * 128 + ks * 32 + kg * 8); \
    bf16x8 a0_ = *reinterpret_cast<const bf16x8*>(htg + (0 * 16 + cl) * 140 + ks * 32 + kg * 8); \
    bf16x8 a1_ = *reinterpret_cast<const bf16x8*>(htg + (1 * 16 + cl) * 140 + ks * 32 + kg * 8); \
    bf16x8 a2_ = *reinterpret_cast<const bf16x8*>(htg + (2 * 16 + cl) * 140 + ks * 32 + kg * 8); \
    bf16x8 a3_ = *reinterpret_cast<const bf16x8*>(htg + (3 * 16 + cl) * 140 + ks * 32 + kg * 8); \
    pac[0][0] = __builtin_amdgcn_mfma_f32_16x16x32_bf16(a0_, w0_, pac[0][0], 0, 0, 0); \
    pac[0][1] = __builtin_amdgcn_mfma_f32_16x16x32_bf16(a0_, w1_, pac[0][1], 0, 0, 0); \
    pac[1][0] = __builtin_amdgcn_mfma_f32_16x16x32_bf16(a1_, w0_, pac[1][0], 0, 0, 0); \
    pac[1][1] = __builtin_amdgcn_mfma_f32_16x16x32_bf16(a1_, w1_, pac[1][1], 0, 0, 0); \
    pac[2][0] = __builtin_amdgcn_mfma_f32_16x16x32_bf16(a2_, w0_, pac[2][0], 0, 0, 0); \
    pac[2][1] = __builtin_amdgcn_mfma_f32_16x16x32_bf16(a2_, w1_, pac[2][1], 0, 0, 0); \
    pac[3][0] = __builtin_amdgcn_mfma_f32_16x16x32_bf16(a3_, w0_, pac[3][0], 0, 0, 0); \
    pac[3][1] = __builtin_amdgcn_mfma_f32_16x16x32_bf16(a3_, w1_, pac[3][1], 0, 0, 0); \
  } \
  _Pragma("unroll") for (int t = 0; t < 4; ++t) { \
    int erow_ = g * 32 + (c) * 8 + t * 2 + (kg >> 1); \
    _Pragma("unroll") for (int ct = 0; ct < 2; ++ct) { \
      int col_ = ncol + ct * 16 + cl; \
      float r1_ = bf2f(s_R1[erow_ * 136 + col_]); \
      float sh_ = 0.f, sg_ = 0.f; \
      _Pragma("unroll") for (int r = 0; r < 4; ++r) { \
        float hv_ = bf2f(htg[(t * 16 + kg * 4 + r) * 140 + col_]); \
        sh_ += hv_; \
        sg_ += fsig(r1_ + pac[t][ct][r]) * hv_; \
      } \
      sh_ += __shfl_xor(sh_, 16); \
      sg_ += __shfl_xor(sg_, 16); \
      if ((kg & 1) == 0) { \
        s_sb[erow_ * 136 + col_] = f2bf(sh_); \
        s_gb[erow_ * 136 + col_] = f2bf(sg_); \
      } \
    } \
  } \
}

// M=64 rows/block, 512 threads (8 waves = 2 rowgroups x 4 colgroups).
// LDS 70656 B -> 2 blocks/CU:
//   s_R1/s_gb alias @0      u16[64][136]  (R1 row consumed before s_gb row written, same wave)
//   s_sb       @17408       u16[64][136]
//   htile      @34816       2 rowgroups x u16[64][140] (pad-140 kills write conflicts)
//   out-stage aliases htile region at the end.
template<int MODE>   // 0=first step (h=0), 1=middle (bf16 h out), 2=last (fp32 out)
__global__ __launch_bounds__(512, 4) void step_k(
    const u16t* __restrict__ fmb,
    const int*  __restrict__ bg32,
    const u16t* __restrict__ Hin,
    const short* __restrict__ wbf,
    const float* __restrict__ bz, const float* __restrict__ urb, const float* __restrict__ bh,
    u16t* __restrict__ Hout, float* __restrict__ houtf, int E)
{
  __shared__ __align__(16) char smem[70656];
  u16t* s_R1  = (u16t*)smem;
  u16t* s_gb  = (u16t*)smem;              // alias (per-row read-then-write, same wave)
  u16t* s_sb  = (u16t*)(smem + 17408);
  u16t* htile = (u16t*)(smem + 34816);

  const int tid = threadIdx.x, wave = tid >> 6, lane = tid & 63;
  const int cl = lane & 15, kg = lane >> 4;
  const int base = blockIdx.x * 64;
  const int g = wave & 1, cg = wave >> 1;
  const int wrow = g * 32, ncol = cg * 32;
  u16t* htg = htile + g * (64 * 140);

  const short* Wzf = wbf;
  const short* Wzh = wbf + 16384;
  const short* Wr  = wbf + 2 * 16384;
  const short* Whf = wbf + 3 * 16384;
  const short* Whh = wbf + 4 * 16384;
  const short* Ur  = wbf + 5 * 16384;

  if (MODE != 0) {
    // ---- phase A: R1 = fmess @ Wr^T + urb -> s_R1 (af scoped, dies after) ----
    {
      bf16x8 af0[2][4];
      #pragma unroll
      for (int rt = 0; rt < 2; ++rt) {
        int ar = base + wrow + rt * 16 + cl;
        if (ar >= E) ar = E - 1;
        #pragma unroll
        for (int ks = 0; ks < 4; ++ks)
          af0[rt][ks] = *reinterpret_cast<const bf16x8*>(fmb + (size_t)ar * 128 + ks * 32 + kg * 8);
      }
      f32x4 racc[2][2];
      #pragma unroll
      for (int rt = 0; rt < 2; ++rt)
        #pragma unroll
        for (int nt = 0; nt < 2; ++nt) racc[rt][nt] = (f32x4){0.f, 0.f, 0.f, 0.f};
      #pragma unroll
      for (int ks = 0; ks < 4; ++ks) {
        #pragma unroll
        for (int nt = 0; nt < 2; ++nt) {
          bf16x8 b = *reinterpret_cast<const bf16x8*>(Wr + (size_t)(ncol + nt * 16 + cl) * 128 + ks * 32 + kg * 8);
          racc[0][nt] = __builtin_amdgcn_mfma_f32_16x16x32_bf16(af0[0][ks], b, racc[0][nt], 0, 0, 0);
          racc[1][nt] = __builtin_amdgcn_mfma_f32_16x16x32_bf16(af0[1][ks], b, racc[1][nt], 0, 0, 0);
        }
      }
      #pragma unroll
      for (int nt = 0; nt < 2; ++nt) {
        int n = ncol + nt * 16 + cl;
        float bias = urb[n];
        #pragma unroll
        for (int rt = 0; rt < 2; ++rt)
          #pragma unroll
          for (int r = 0; r < 4; ++r)
            s_R1[(wrow + rt * 16 + kg * 4 + r) * 136 + n] = f2bf(racc[rt][nt][r] + bias);
      }
    }
    // (chunk-0's first __syncthreads publishes s_R1)

    // ---- phase B: 4 gather chunks, P on the fly ----
    int idxs[4];
    #pragma unroll
    for (int c = 0; c < 4; ++c) {
      int e_g = base + g * 32 + c * 8 + cg * 2 + (cl >> 3);
      if (e_g >= E) e_g = 0;
      idxs[c] = bg32[(size_t)e_g * 8 + (cl & 7)];
    }
    uint4 A0, A1, A2, A3, B0, B1, B2, B3;
    ANLOAD(A0, A1, A2, A3, 0)
    CHUNK(0, A0, A1, A2, A3, B0, B1, B2, B3, 0)
    CHUNK(1, B0, B1, B2, B3, A0, A1, A2, A3, 0)
    CHUNK(2, A0, A1, A2, A3, B0, B1, B2, B3, 0)
    CHUNK(3, B0, B1, B2, B3, A0, A1, A2, A3, 1)
    __syncthreads();   // s_sb/s_gb complete; htile free
  }

  // ---- phase C: epilogue GEMMs (af reloaded) ----
  bf16x8 af[2][4];
  #pragma unroll
  for (int rt = 0; rt < 2; ++rt) {
    int ar = base + wrow + rt * 16 + cl;
    if (ar >= E) ar = E - 1;
    #pragma unroll
    for (int ks = 0; ks < 4; ++ks)
      af[rt][ks] = *reinterpret_cast<const bf16x8*>(fmb + (size_t)ar * 128 + ks * 32 + kg * 8);
  }

  // pre-GEMM: af·Whf + gated·Whh -> tanh -> stash into s_gb
  {
    f32x4 acc[2][2];
    #pragma unroll
    for (int rt = 0; rt < 2; ++rt)
      #pragma unroll
      for (int nt = 0; nt < 2; ++nt) acc[rt][nt] = (f32x4){0.f, 0.f, 0.f, 0.f};
    #pragma unroll
    for (int ks = 0; ks < 4; ++ks) {
      bf16x8 ag0, ag1;
      if (MODE != 0) {
        ag0 = *reinterpret_cast<const bf16x8*>(s_gb + (wrow + cl) * 136 + ks * 32 + kg * 8);
        ag1 = *reinterpret_cast<const bf16x8*>(s_gb + (wrow + 16 + cl) * 136 + ks * 32 + kg * 8);
      }
      #pragma unroll
      for (int nt = 0; nt < 2; ++nt) {
        int n = ncol + nt * 16 + cl;
        bf16x8 b1 = *reinterpret_cast<const bf16x8*>(Whf + (size_t)n * 128 + ks * 32 + kg * 8);
        acc[0][nt] = __builtin_amdgcn_mfma_f32_16x16x32_bf16(af[0][ks], b1, acc[0][nt], 0, 0, 0);
        acc[1][nt] = __builtin_amdgcn_mfma_f32_16x16x32_bf16(af[1][ks], b1, acc[1][nt], 0, 0, 0);
        if (MODE != 0) {
          bf16x8 b2 = *reinterpret_cast<const bf16x8*>(Whh + (size_t)n * 128 + ks * 32 + kg * 8);
          acc[0][nt] = __builtin_amdgcn_mfma_f32_16x16x32_bf16(ag0, b2, acc[0][nt], 0, 0, 0);
          acc[1][nt] = __builtin_amdgcn_mfma_f32_16x16x32_bf16(ag1, b2, acc[1][nt], 0, 0, 0);
        }
      }
    }
    __syncthreads();   // all s_gb frag reads done before overwrite
    #pragma unroll
    for (int nt = 0; nt < 2; ++nt) {
      int n = ncol + nt * 16 + cl;
      float bhv = bh[n];
      #pragma unroll
      for (int rt = 0; rt < 2; ++rt)
        #pragma unroll
        for (int r = 0; r < 4; ++r)
          s_gb[(wrow + rt * 16 + kg * 4 + r) * 136 + n] = f2bf(ftanh(acc[rt][nt][r] + bhv));
    }
  }

  // z-GEMM + GRU epilogue
  float nh_sv[2][2][4];
  {
    f32x4 acc[2][2];
    #pragma unroll
    for (int rt = 0; rt < 2; ++rt)
      #pragma unroll
      for (int nt = 0; nt < 2; ++nt) acc[rt][nt] = (f32x4){0.f, 0.f, 0.f, 0.f};
    #pragma unroll
    for (int ks = 0; ks < 4; ++ks) {
      bf16x8 as0, as1;
      if (MODE != 0) {
        as0 = *reinterpret_cast<const bf16x8*>(s_sb + (wrow + cl) * 136 + ks * 32 + kg * 8);
        as1 = *reinterpret_cast<const bf16x8*>(s_sb + (wrow + 16 + cl) * 136 + ks * 32 + kg * 8);
      }
      #pragma unroll
      for (int nt = 0; nt < 2; ++nt) {
        int n = ncol + nt * 16 + cl;
        bf16x8 b1 = *reinterpret_cast<const bf16x8*>(Wzf + (size_t)n * 128 + ks * 32 + kg * 8);
        acc[0][nt] = __builtin_amdgcn_mfma_f32_16x16x32_bf16(af[0][ks], b1, acc[0][nt], 0, 0, 0);
        acc[1][nt] = __builtin_amdgcn_mfma_f32_16x16x32_bf16(af[1][ks], b1, acc[1][nt], 0, 0, 0);
        if (MODE != 0) {
          bf16x8 b2 = *reinterpret_cast<const bf16x8*>(Wzh + (size_t)n * 128 + ks * 32 + kg * 8);
          acc[0][nt] = __builtin_amdgcn_mfma_f32_16x16x32_bf16(as0, b2, acc[0][nt], 0, 0, 0);
          acc[1][nt] = __builtin_amdgcn_mfma_f32_16x16x32_bf16(as1, b2, acc[1][nt], 0, 0, 0);
        }
      }
    }
    #pragma unroll
    for (int nt = 0; nt < 2; ++nt) {
      int n = ncol + nt * 16 + cl;
      float bzv = bz[n];
      #pragma unroll
      for (int rt = 0; rt < 2; ++rt)
        #pragma unroll
        for (int r = 0; r < 4; ++r) {
          int rowt = wrow + rt * 16 + kg * 4 + r;
          int e = base + rowt;
          float z   = fsig(acc[rt][nt][r] + bzv);
          float pre = bf2f(s_gb[rowt * 136 + n]);   // own cell
          float sh  = (MODE == 0) ? 0.f : bf2f(s_sb[rowt * 136 + n]);
          float nh  = (1.f - z) * sh + z * pre;
          if (e == 0) nh = 0.f;
          nh_sv[rt][nt][r] = nh;
        }
    }
  }
  __syncthreads();   // all s_sb/s_gb readers done

  // ---- phase D: stage + coalesced store (stage aliases htile region) ----
  if (MODE == 2) {
    float* so = (float*)(smem + 34816);   // fp32 [64][132] = 33792 B
    #pragma unroll
    for (int nt = 0; nt < 2; ++nt) {
      int n = ncol + nt * 16 + cl;
      #pragma unroll
      for (int rt = 0; rt < 2; ++rt)
        #pragma unroll
        for (int r = 0; r < 4; ++r)
          so[(wrow + rt * 16 + kg * 4 + r) * 132 + n] = nh_sv[rt][nt][r];
    }
    __syncthreads();
    #pragma unroll
    for (int it = 0; it < 4; ++it) {
      int slot = it * 512 + tid;
      int row = slot >> 5, seg = slot & 31;
      if (base + row < E)
        *reinterpret_cast<float4*>(houtf + (size_t)(base + row) * 128 + seg * 4) =
            *reinterpret_cast<const float4*>(so + row * 132 + seg * 4);
    }
  } else {
    u16t* so = (u16t*)(smem + 34816);     // u16 [64][128] = 16384 B
    #pragma unroll
    for (int nt = 0; nt < 2; ++nt) {
      int n = ncol + nt * 16 + cl;
      #pragma unroll
      for (int rt = 0; rt < 2; ++rt)
        #pragma unroll
        for (int r = 0; r < 4; ++r)
          so[(wrow + rt * 16 + kg * 4 + r) * 128 + n] = f2bf(nh_sv[rt][nt][r]);
    }
    __syncthreads();
    #pragma unroll
    for (int it = 0; it < 2; ++it) {
      int slot = it * 512 + tid;
      int row = slot >> 4, seg = slot & 15;
      if (base + row < E)
        *reinterpret_cast<uint4*>(Hout + (size_t)(base + row) * 128 + seg * 8) =
            *reinterpret_cast<const uint4*>(so + row * 128 + seg * 8);
    }
  }
}

extern "C" void kernel_launch(void* const* d_in, const int* in_sizes, int n_in,
                              void* d_out, int out_size, void* d_ws, size_t ws_size,
                              hipStream_t stream) {
  const float* fmess = (const float*)d_in[0];
  const int*   bg    = (const int*)d_in[1];
  const float* Wz    = (const float*)d_in[2];
  const float* bz    = (const float*)d_in[3];
  const float* Wrw   = (const float*)d_in[4];
  const float* Urw   = (const float*)d_in[5];
  const float* urb   = (const float*)d_in[6];
  const float* Wh    = (const float*)d_in[7];
  const float* bh    = (const float*)d_in[8];
  float* out = (float*)d_out;

  const int E = in_sizes[0] / 128;
  const size_t EH = (size_t)E * 128;
  const size_t wshorts = 6 * 16384;

  // ws (~82 MB, proven): HA (EH u16) | fmb (EH u16) | bg32 (E*8 int) | wbf | flag
  u16t* HA   = (u16t*)d_ws;
  u16t* fmb  = HA + EH;
  int*  bg32 = (int*)(fmb + EH);
  short* wbf = (short*)(bg32 + (size_t)E * 8);
  int*  flag = (int*)(wbf + wshorts);
  // HB in d_out (38.4 MB <= 76.8; dead before the final fp32 write)
  u16t* HB = (u16t*)d_out;

  conv_weights<<<384, 256, 0, stream>>>(Wz, Wrw, Urw, Wh, wbf);
  detect64<<<1, 64, 0, stream>>>(bg, flag);
  compact_bg<<<(E * 8 + 255) / 256, 256, 0, stream>>>(bg, flag, bg32, E * 8);
  conv_fmess<<<(int)((EH / 8 + 255) / 256), 256, 0, stream>>>(fmess, fmb, EH / 8);

  const int grid = (E + 63) / 64;
  // s0 -> B ; s1 B->A ; s2 A->B ; s3 B->A ; s4 A -> fp32 out
  step_k<0><<<grid, 512, 0, stream>>>(fmb, bg32, nullptr, wbf, bz, urb, bh, HB, nullptr, E);
  step_k<1><<<grid, 512, 0, stream>>>(fmb, bg32, HB, wbf, bz, urb, bh, HA, nullptr, E);
  step_k<1><<<grid, 512, 0, stream>>>(fmb, bg32, HA, wbf, bz, urb, bh, HB, nullptr, E);
  step_k<1><<<grid, 512, 0, stream>>>(fmb, bg32, HB, wbf, bz, urb, bh, HA, nullptr, E);
  step_k<2><<<grid, 512, 0, stream>>>(fmb, bg32, HA, wbf, bz, urb, bh, nullptr, out, E);
}

// Round 11
// 777.904 us; speedup vs baseline: 1.6418x; 1.6418x over previous
//
#include <hip/hip_runtime.h>
#include <cstddef>
#include <cstdint>

typedef __attribute__((ext_vector_type(8))) short bf16x8;
typedef __attribute__((ext_vector_type(4))) float f32x4;
typedef __attribute__((ext_vector_type(2))) float f32x2;
typedef unsigned int u32t;
typedef unsigned short u16t;
typedef unsigned char u8t;

__device__ inline u16t f2bf(float f) {
  union { float f; unsigned u; } c; c.f = f;
  return (u16t)((c.u + 0x7FFFu + ((c.u >> 16) & 1u)) >> 16);
}
__device__ inline float ubits(u32t u) { union { u32t u; float f; } c; c.u = u; return c.f; }
__device__ inline float bf2f(u16t u) { return ubits(((u32t)u) << 16); }
__device__ inline float fsig(float x) { return __builtin_amdgcn_rcpf(1.f + __expf(-x)); }
__device__ inline float ftanh(float x) {
  float t = __expf(-2.f * fabsf(x));
  return copysignf((1.f - t) * __builtin_amdgcn_rcpf(1.f + t), x);
}
__device__ inline u32t f32x4_to_fp8(float a, float b, float c, float d) {
  int v = __builtin_amdgcn_cvt_pk_fp8_f32(a, b, 0, false);
  v = __builtin_amdgcn_cvt_pk_fp8_f32(c, d, v, true);
  return (u32t)v;
}

// bf16 weight mats, row-major [128][128]:
// 0: Wzf  1: Wzh  2: Wr  3: Whf  4: Whh  5: Ur
__global__ __launch_bounds__(256) void conv_weights(
    const float* __restrict__ Wz, const float* __restrict__ Wr,
    const float* __restrict__ Ur, const float* __restrict__ Wh,
    short* __restrict__ out)
{
  int i = blockIdx.x * 256 + threadIdx.x;
  if (i >= 6 * 16384) return;
  int mat = i >> 14, idx = i & 16383;
  int o = idx >> 7, c = idx & 127;
  float v = 0.f;
  switch (mat) {
    case 0: v = Wz[o * 256 + c];        break;
    case 1: v = Wz[o * 256 + 128 + c];  break;
    case 2: v = Wr[o * 128 + c];        break;
    case 3: v = Wh[o * 256 + c];        break;
    case 4: v = Wh[o * 256 + 128 + c];  break;
    case 5: v = Ur[o * 128 + c];        break;
  }
  out[i] = (short)f2bf(v);
}

__global__ __launch_bounds__(256) void conv_fmess(const float* __restrict__ src,
                                                  u16t* __restrict__ dst, size_t n8)
{
  size_t i = (size_t)blockIdx.x * 256 + threadIdx.x;
  if (i >= n8) return;
  const float4 a = *reinterpret_cast<const float4*>(src + i * 8);
  const float4 b = *reinterpret_cast<const float4*>(src + i * 8 + 4);
  uint4 o;
  o.x = ((u32t)f2bf(a.y) << 16) | f2bf(a.x);
  o.y = ((u32t)f2bf(a.w) << 16) | f2bf(a.z);
  o.z = ((u32t)f2bf(b.y) << 16) | f2bf(b.x);
  o.w = ((u32t)f2bf(b.w) << 16) | f2bf(b.z);
  *reinterpret_cast<uint4*>(dst + i * 8) = o;
}

__global__ void detect64(const int* __restrict__ bg, int* __restrict__ flag) {
  int t = threadIdx.x;
  int v = bg[2 * t + 1];
  unsigned long long m = __ballot(v == 0);
  if (t == 0) *flag = (m == ~0ull) ? 1 : 0;
}

__global__ __launch_bounds__(256) void compact_bg(const int* __restrict__ bg,
                                                  const int* __restrict__ flag,
                                                  int* __restrict__ bg32, int n)
{
  int i = blockIdx.x * 256 + threadIdx.x;
  if (i < n) bg32[i] = (*flag) ? bg[2 * (size_t)i] : bg[i];
}

// ---- gather macros: half-wave owns rows; 2-deep reg pipeline ----
#define GLD(H0, H1, H2, H3, P0, P1, P2, P3, q, nbb) { \
  int i0_ = __shfl(idx_all, (hf * 4 + (q)) * 8 + (nbb) + 0); \
  int i1_ = __shfl(idx_all, (hf * 4 + (q)) * 8 + (nbb) + 1); \
  int i2_ = __shfl(idx_all, (hf * 4 + (q)) * 8 + (nbb) + 2); \
  int i3_ = __shfl(idx_all, (hf * 4 + (q)) * 8 + (nbb) + 3); \
  H0 = *reinterpret_cast<const uint2*>(Hin + (size_t)i0_ * 128 + l5 * 4); \
  H1 = *reinterpret_cast<const uint2*>(Hin + (size_t)i1_ * 128 + l5 * 4); \
  H2 = *reinterpret_cast<const uint2*>(Hin + (size_t)i2_ * 128 + l5 * 4); \
  H3 = *reinterpret_cast<const uint2*>(Hin + (size_t)i3_ * 128 + l5 * 4); \
  P0 = *reinterpret_cast<const u32t*>(Pin + (size_t)i0_ * 128 + l5 * 4); \
  P1 = *reinterpret_cast<const u32t*>(Pin + (size_t)i1_ * 128 + l5 * 4); \
  P2 = *reinterpret_cast<const u32t*>(Pin + (size_t)i2_ * 128 + l5 * 4); \
  P3 = *reinterpret_cast<const u32t*>(Pin + (size_t)i3_ * 128 + l5 * 4); \
}

#define PRN(HV, PW) { \
  f32x2 plo_ = __builtin_amdgcn_cvt_pk_f32_fp8((int)(PW), false); \
  f32x2 phi_ = __builtin_amdgcn_cvt_pk_f32_fp8((int)(PW), true); \
  float h0_ = ubits(HV.x << 16), h1_ = ubits(HV.x & 0xffff0000u); \
  float h2_ = ubits(HV.y << 16), h3_ = ubits(HV.y & 0xffff0000u); \
  s0 += h0_; g0 += fsig(r10 + plo_.x) * h0_; \
  s1 += h1_; g1 += fsig(r11 + plo_.y) * h1_; \
  s2 += h2_; g2 += fsig(r12 + phi_.x) * h2_; \
  s3 += h3_; g3 += fsig(r13 + phi_.y) * h3_; \
}

#define PR4(HH0, HH1, HH2, HH3, PP0, PP1, PP2, PP3) \
  PRN(HH0, PP0) PRN(HH1, PP1) PRN(HH2, PP2) PRN(HH3, PP3)

#define INITR(q) { \
  int rl_ = wave * 8 + hf * 4 + (q); \
  uint2 rp_ = *reinterpret_cast<const uint2*>(s_R1 + rl_ * 136 + l5 * 4); \
  r10 = ubits(rp_.x << 16); r11 = ubits(rp_.x & 0xffff0000u); \
  r12 = ubits(rp_.y << 16); r13 = ubits(rp_.y & 0xffff0000u); \
  s0 = s1 = s2 = s3 = 0.f; g0 = g1 = g2 = g3 = 0.f; \
}

#define FINR(q) { \
  int rl_ = wave * 8 + hf * 4 + (q); \
  uint2 sp_, gp_; \
  sp_.x = ((u32t)f2bf(s1) << 16) | f2bf(s0); \
  sp_.y = ((u32t)f2bf(s3) << 16) | f2bf(s2); \
  gp_.x = ((u32t)f2bf(g1) << 16) | f2bf(g0); \
  gp_.y = ((u32t)f2bf(g3) << 16) | f2bf(g2); \
  *reinterpret_cast<uint2*>(s_sb + rl_ * 136 + l5 * 4) = sp_; \
  *reinterpret_cast<uint2*>(s_gb + rl_ * 136 + l5 * 4) = gp_; \
}

// M=64 rows/block, 512 threads (8 waves = 2 rowgroups x 4 colgroups, 2 row-tiles/wave).
// LDS 52224 B: s_R1 @0 (also z-stash), s_sb @17408, s_gb @34816 (all u16[64][136]).
// MODE2 fp32 out-stage (stride 132) aliases s_sb+s_gb.
template<int MODE>   // 0=first step (h=0), 1=middle, 2=last (fp32 out)
__global__ __launch_bounds__(512, 4) void step_k(
    const u16t* __restrict__ fmb,
    const int*  __restrict__ bg32,
    const u16t* __restrict__ Hin,
    const u8t*  __restrict__ Pin,
    const short* __restrict__ wbf,
    const float* __restrict__ bz, const float* __restrict__ urb, const float* __restrict__ bh,
    u16t* __restrict__ Hout, u8t* __restrict__ Pout, float* __restrict__ houtf, int E)
{
  __shared__ __align__(16) char smem[52224];
  u16t* s_R1 = (u16t*)smem;
  u16t* s_sb = (u16t*)(smem + 17408);
  u16t* s_gb = (u16t*)(smem + 34816);

  const int tid = threadIdx.x, wave = tid >> 6, lane = tid & 63;
  const int cl = lane & 15, kg = lane >> 4;
  const int l5 = lane & 31, hf = lane >> 5;
  const int base = blockIdx.x * 64;
  const int wrow = (wave & 1) * 32, ncol = (wave >> 1) * 32;

  const short* Wzf = wbf;
  const short* Wzh = wbf + 16384;
  const short* Wr  = wbf + 2 * 16384;
  const short* Whf = wbf + 3 * 16384;
  const short* Whh = wbf + 4 * 16384;
  const short* Ur  = wbf + 5 * 16384;

  // af fragments straight from global (fmb tile is L2-hot), held in regs
  bf16x8 af[2][4];
  #pragma unroll
  for (int rt = 0; rt < 2; ++rt) {
    int ar = base + wrow + rt * 16 + cl;
    if (ar >= E) ar = E - 1;
    #pragma unroll
    for (int ks = 0; ks < 4; ++ks)
      af[rt][ks] = *reinterpret_cast<const bf16x8*>(fmb + (size_t)ar * 128 + ks * 32 + kg * 8);
  }

  int idx_all = 0;
  if (MODE != 0) {
    int er = base + wave * 8 + (lane >> 3);
    if (er >= E) er = 0;
    idx_all = bg32[(size_t)er * 8 + (lane & 7)];
  }

  if (MODE != 0) {
    // ---- R1 = fmess @ Wr^T + urb -> s_R1 ----
    f32x4 racc[2][2];
    #pragma unroll
    for (int rt = 0; rt < 2; ++rt)
      #pragma unroll
      for (int nt = 0; nt < 2; ++nt) racc[rt][nt] = (f32x4){0.f, 0.f, 0.f, 0.f};
    #pragma unroll
    for (int ks = 0; ks < 4; ++ks) {
      #pragma unroll
      for (int nt = 0; nt < 2; ++nt) {
        bf16x8 b = *reinterpret_cast<const bf16x8*>(Wr + (size_t)(ncol + nt * 16 + cl) * 128 + ks * 32 + kg * 8);
        #pragma unroll
        for (int rt = 0; rt < 2; ++rt)
          racc[rt][nt] = __builtin_amdgcn_mfma_f32_16x16x32_bf16(af[rt][ks], b, racc[rt][nt], 0, 0, 0);
      }
    }
    #pragma unroll
    for (int nt = 0; nt < 2; ++nt) {
      int n = ncol + nt * 16 + cl;
      float bias = urb[n];
      #pragma unroll
      for (int rt = 0; rt < 2; ++rt)
        #pragma unroll
        for (int r = 0; r < 4; ++r)
          s_R1[(wrow + rt * 16 + kg * 4 + r) * 136 + n] = f2bf(racc[rt][nt][r] + bias);
    }
    __syncthreads();

    // ---- gather: 8 rows per wave, 2-deep pipeline ----
    uint2 HA0, HA1, HA2, HA3, HB0, HB1, HB2, HB3;
    u32t  PA0, PA1, PA2, PA3, PB0, PB1, PB2, PB3;
    float s0, s1, s2, s3, g0, g1, g2, g3, r10, r11, r12, r13;

    GLD(HA0, HA1, HA2, HA3, PA0, PA1, PA2, PA3, 0, 0)
    GLD(HB0, HB1, HB2, HB3, PB0, PB1, PB2, PB3, 0, 4)
    INITR(0)
    PR4(HA0, HA1, HA2, HA3, PA0, PA1, PA2, PA3)
    GLD(HA0, HA1, HA2, HA3, PA0, PA1, PA2, PA3, 1, 0)
    PR4(HB0, HB1, HB2, HB3, PB0, PB1, PB2, PB3)
    FINR(0)
    GLD(HB0, HB1, HB2, HB3, PB0, PB1, PB2, PB3, 1, 4)
    INITR(1)
    PR4(HA0, HA1, HA2, HA3, PA0, PA1, PA2, PA3)
    GLD(HA0, HA1, HA2, HA3, PA0, PA1, PA2, PA3, 2, 0)
    PR4(HB0, HB1, HB2, HB3, PB0, PB1, PB2, PB3)
    FINR(1)
    GLD(HB0, HB1, HB2, HB3, PB0, PB1, PB2, PB3, 2, 4)
    INITR(2)
    PR4(HA0, HA1, HA2, HA3, PA0, PA1, PA2, PA3)
    GLD(HA0, HA1, HA2, HA3, PA0, PA1, PA2, PA3, 3, 0)
    PR4(HB0, HB1, HB2, HB3, PB0, PB1, PB2, PB3)
    FINR(2)
    GLD(HB0, HB1, HB2, HB3, PB0, PB1, PB2, PB3, 3, 4)
    INITR(3)
    PR4(HA0, HA1, HA2, HA3, PA0, PA1, PA2, PA3)
    PR4(HB0, HB1, HB2, HB3, PB0, PB1, PB2, PB3)
    FINR(3)
    __syncthreads();
  }

  // ---- 4a: z = sigmoid(af·Wzf + sum·Wzh + bz), stash bf16 into s_R1 ----
  {
    f32x4 acc[2][2];
    #pragma unroll
    for (int rt = 0; rt < 2; ++rt)
      #pragma unroll
      for (int nt = 0; nt < 2; ++nt) acc[rt][nt] = (f32x4){0.f, 0.f, 0.f, 0.f};
    #pragma unroll
    for (int ks = 0; ks < 4; ++ks) {
      bf16x8 as0, as1;
      if (MODE != 0) {
        as0 = *reinterpret_cast<const bf16x8*>(s_sb + (wrow + cl) * 136 + ks * 32 + kg * 8);
        as1 = *reinterpret_cast<const bf16x8*>(s_sb + (wrow + 16 + cl) * 136 + ks * 32 + kg * 8);
      }
      #pragma unroll
      for (int nt = 0; nt < 2; ++nt) {
        int n = ncol + nt * 16 + cl;
        bf16x8 b1 = *reinterpret_cast<const bf16x8*>(Wzf + (size_t)n * 128 + ks * 32 + kg * 8);
        acc[0][nt] = __builtin_amdgcn_mfma_f32_16x16x32_bf16(af[0][ks], b1, acc[0][nt], 0, 0, 0);
        acc[1][nt] = __builtin_amdgcn_mfma_f32_16x16x32_bf16(af[1][ks], b1, acc[1][nt], 0, 0, 0);
        if (MODE != 0) {
          bf16x8 b2 = *reinterpret_cast<const bf16x8*>(Wzh + (size_t)n * 128 + ks * 32 + kg * 8);
          acc[0][nt] = __builtin_amdgcn_mfma_f32_16x16x32_bf16(as0, b2, acc[0][nt], 0, 0, 0);
          acc[1][nt] = __builtin_amdgcn_mfma_f32_16x16x32_bf16(as1, b2, acc[1][nt], 0, 0, 0);
        }
      }
    }
    #pragma unroll
    for (int nt = 0; nt < 2; ++nt) {
      int n = ncol + nt * 16 + cl;
      float bzv = bz[n];
      #pragma unroll
      for (int rt = 0; rt < 2; ++rt)
        #pragma unroll
        for (int r = 0; r < 4; ++r)
          s_R1[(wrow + rt * 16 + kg * 4 + r) * 136 + n] = f2bf(fsig(acc[rt][nt][r] + bzv));
    }
  }

  // ---- 4b: pre = tanh(af·Whf + gated·Whh + bh); epilogue ----
  float nh_sv[2][2][4];
  {
    f32x4 acc[2][2];
    #pragma unroll
    for (int rt = 0; rt < 2; ++rt)
      #pragma unroll
      for (int nt = 0; nt < 2; ++nt) acc[rt][nt] = (f32x4){0.f, 0.f, 0.f, 0.f};
    #pragma unroll
    for (int ks = 0; ks < 4; ++ks) {
      bf16x8 ag0, ag1;
      if (MODE != 0) {
        ag0 = *reinterpret_cast<const bf16x8*>(s_gb + (wrow + cl) * 136 + ks * 32 + kg * 8);
        ag1 = *reinterpret_cast<const bf16x8*>(s_gb + (wrow + 16 + cl) * 136 + ks * 32 + kg * 8);
      }
      #pragma unroll
      for (int nt = 0; nt < 2; ++nt) {
        int n = ncol + nt * 16 + cl;
        bf16x8 b1 = *reinterpret_cast<const bf16x8*>(Whf + (size_t)n * 128 + ks * 32 + kg * 8);
        acc[0][nt] = __builtin_amdgcn_mfma_f32_16x16x32_bf16(af[0][ks], b1, acc[0][nt], 0, 0, 0);
        acc[1][nt] = __builtin_amdgcn_mfma_f32_16x16x32_bf16(af[1][ks], b1, acc[1][nt], 0, 0, 0);
        if (MODE != 0) {
          bf16x8 b2 = *reinterpret_cast<const bf16x8*>(Whh + (size_t)n * 128 + ks * 32 + kg * 8);
          acc[0][nt] = __builtin_amdgcn_mfma_f32_16x16x32_bf16(ag0, b2, acc[0][nt], 0, 0, 0);
          acc[1][nt] = __builtin_amdgcn_mfma_f32_16x16x32_bf16(ag1, b2, acc[1][nt], 0, 0, 0);
        }
      }
    }
    #pragma unroll
    for (int nt = 0; nt < 2; ++nt) {
      int n = ncol + nt * 16 + cl;
      float bhv = bh[n];
      #pragma unroll
      for (int rt = 0; rt < 2; ++rt)
        #pragma unroll
        for (int r = 0; r < 4; ++r) {
          int rowt = wrow + rt * 16 + kg * 4 + r;
          int e = base + rowt;
          float pre = ftanh(acc[rt][nt][r] + bhv);
          float z   = bf2f(s_R1[rowt * 136 + n]);
          float sh  = (MODE == 0) ? 0.f : bf2f(s_sb[rowt * 136 + n]);
          float nh  = (1.f - z) * sh + z * pre;
          if (e == 0) nh = 0.f;
          nh_sv[rt][nt][r] = nh;
        }
    }
  }

  // ---- outputs ----
  if (MODE == 2) {
    __syncthreads();
    float* so = (float*)(smem + 17408);   // stride 132 fp32, 64 rows
    #pragma unroll
    for (int nt = 0; nt < 2; ++nt) {
      int n = ncol + nt * 16 + cl;
      #pragma unroll
      for (int rt = 0; rt < 2; ++rt)
        #pragma unroll
        for (int r = 0; r < 4; ++r)
          so[(wrow + rt * 16 + kg * 4 + r) * 132 + n] = nh_sv[rt][nt][r];
    }
    __syncthreads();
    #pragma unroll
    for (int it = 0; it < 4; ++it) {
      int slot = it * 512 + tid;
      int row = slot >> 5, seg = slot & 31;
      if (base + row < E)
        *reinterpret_cast<float4*>(houtf + (size_t)(base + row) * 128 + seg * 4) =
            *reinterpret_cast<const float4*>(so + row * 132 + seg * 4);
    }
  } else {
    __syncthreads();   // all s_sb/s_gb readers done
    #pragma unroll
    for (int nt = 0; nt < 2; ++nt) {
      int n = ncol + nt * 16 + cl;
      #pragma unroll
      for (int rt = 0; rt < 2; ++rt)
        #pragma unroll
        for (int r = 0; r < 4; ++r)
          s_sb[(wrow + rt * 16 + kg * 4 + r) * 136 + n] = f2bf(nh_sv[rt][nt][r]);
    }
    __syncthreads();
    // P_next = h_next @ Ur^T -> s_gb (bf16)
    f32x4 pacc[2][2];
    #pragma unroll
    for (int rt = 0; rt < 2; ++rt)
      #pragma unroll
      for (int nt = 0; nt < 2; ++nt) pacc[rt][nt] = (f32x4){0.f, 0.f, 0.f, 0.f};
    #pragma unroll
    for (int ks = 0; ks < 4; ++ks) {
      bf16x8 ah0 = *reinterpret_cast<const bf16x8*>(s_sb + (wrow + cl) * 136 + ks * 32 + kg * 8);
      bf16x8 ah1 = *reinterpret_cast<const bf16x8*>(s_sb + (wrow + 16 + cl) * 136 + ks * 32 + kg * 8);
      #pragma unroll
      for (int nt = 0; nt < 2; ++nt) {
        bf16x8 b = *reinterpret_cast<const bf16x8*>(Ur + (size_t)(ncol + nt * 16 + cl) * 128 + ks * 32 + kg * 8);
        pacc[0][nt] = __builtin_amdgcn_mfma_f32_16x16x32_bf16(ah0, b, pacc[0][nt], 0, 0, 0);
        pacc[1][nt] = __builtin_amdgcn_mfma_f32_16x16x32_bf16(ah1, b, pacc[1][nt], 0, 0, 0);
      }
    }
    #pragma unroll
    for (int nt = 0; nt < 2; ++nt) {
      int n = ncol + nt * 16 + cl;
      #pragma unroll
      for (int rt = 0; rt < 2; ++rt)
        #pragma unroll
        for (int r = 0; r < 4; ++r)
          s_gb[(wrow + rt * 16 + kg * 4 + r) * 136 + n] = f2bf(pacc[rt][nt][r]);
    }
    __syncthreads();
    // coalesced H store (bf16 rows)
    #pragma unroll
    for (int it = 0; it < 2; ++it) {
      int slot = it * 512 + tid;
      int row = slot >> 4, seg = slot & 15;
      if (base + row < E)
        *reinterpret_cast<uint4*>(Hout + (size_t)(base + row) * 128 + seg * 8) =
            *reinterpret_cast<const uint4*>(s_sb + row * 136 + seg * 8);
    }
    // coalesced P store (fp8 rows)
    #pragma unroll
    for (int it = 0; it < 4; ++it) {
      int slot = it * 512 + tid;
      int row = slot >> 5, cg = slot & 31;
      if (base + row < E) {
        uint2 pv = *reinterpret_cast<const uint2*>(s_gb + row * 136 + cg * 4);
        float p0 = ubits(pv.x << 16), p1 = ubits(pv.x & 0xffff0000u);
        float p2 = ubits(pv.y << 16), p3 = ubits(pv.y & 0xffff0000u);
        *reinterpret_cast<u32t*>(Pout + (size_t)(base + row) * 128 + cg * 4) =
            f32x4_to_fp8(p0, p1, p2, p3);
      }
    }
  }
}

extern "C" void kernel_launch(void* const* d_in, const int* in_sizes, int n_in,
                              void* d_out, int out_size, void* d_ws, size_t ws_size,
                              hipStream_t stream) {
  const float* fmess = (const float*)d_in[0];
  const int*   bg    = (const int*)d_in[1];
  const float* Wz    = (const float*)d_in[2];
  const float* bz    = (const float*)d_in[3];
  const float* Wrw   = (const float*)d_in[4];
  const float* Urw   = (const float*)d_in[5];
  const float* urb   = (const float*)d_in[6];
  const float* Wh    = (const float*)d_in[7];
  const float* bh    = (const float*)d_in[8];
  float* out = (float*)d_out;

  const int E = in_sizes[0] / 128;
  const size_t EH = (size_t)E * 128;
  const size_t wshorts = 6 * 16384;

  // ws (~101 MB, proven): HA u16 | PA u8 | fmb u16 | bg32 int | wbf | flag
  u16t* HA   = (u16t*)d_ws;
  u8t*  PA   = (u8t*)(HA + EH);
  u16t* fmb  = (u16t*)(PA + EH);
  int*  bg32 = (int*)(fmb + EH);
  short* wbf = (short*)(bg32 + (size_t)E * 8);
  int*  flag = (int*)(wbf + wshorts);
  // B-set in d_out (dead before the final fp32 write)
  u16t* HB = (u16t*)d_out;
  u8t*  PB = (u8t*)(HB + EH);

  conv_weights<<<384, 256, 0, stream>>>(Wz, Wrw, Urw, Wh, wbf);
  detect64<<<1, 64, 0, stream>>>(bg, flag);
  compact_bg<<<(E * 8 + 255) / 256, 256, 0, stream>>>(bg, flag, bg32, E * 8);
  conv_fmess<<<(int)((EH / 8 + 255) / 256), 256, 0, stream>>>(fmess, fmb, EH / 8);

  const int grid = (E + 63) / 64;
  // s0 -> B ; s1 B->A ; s2 A->B ; s3 B->A ; s4 A -> fp32 out
  step_k<0><<<grid, 512, 0, stream>>>(fmb, bg32, nullptr, nullptr, wbf, bz, urb, bh, HB, PB, nullptr, E);
  step_k<1><<<grid, 512, 0, stream>>>(fmb, bg32, HB, PB, wbf, bz, urb, bh, HA, PA, nullptr, E);
  step_k<1><<<grid, 512, 0, stream>>>(fmb, bg32, HA, PA, wbf, bz, urb, bh, HB, PB, nullptr, E);
  step_k<1><<<grid, 512, 0, stream>>>(fmb, bg32, HB, PB, wbf, bz, urb, bh, HA, PA, nullptr, E);
  step_k<2><<<grid, 512, 0, stream>>>(fmb, bg32, HA, PA, wbf, bz, urb, bh, nullptr, nullptr, out, E);
}